// Round 6
// baseline (215.505 us; speedup 1.0000x reference)
//
#include <hip/hip_runtime.h>
#include <math.h>

#define DD 128
#define NSRC 8
#define EMAX 32          // 32*64 = 2048 >= (m+1)(m+2)/2  ->  m <= 62 fast path
#define MFAST 62
#define LOG_2PI 1.83787706640934548356f
#define LN2F 0.69314718055994531f
#define EPSF 1e-6f

// e -> row index within a packed lower triangle (row r has r+1 elements).
__device__ inline int tri_row_of(int e) {
    float f = sqrtf(8.f * (float)e + 1.f);
    int r = (int)((f - 1.f) * 0.5f);
    if ((r + 1) * (r + 2) / 2 <= e) ++r;
    else if (r * (r + 1) / 2 > e) --r;
    return r;
}

// ---------------------------------------------------------------------------
// K1: fused  (a) miss_mask layout detect  (b) Q_s = (I-W) D^-1 (I-W)^T
//            (c) ldS[s] = logdet Sigma_s
// ---------------------------------------------------------------------------
__global__ __launch_bounds__(128) void k_precompute(
    const float* __restrict__ W, const float* __restrict__ ls2,
    const unsigned int* __restrict__ mw, int n_words,
    float* __restrict__ Q, float* __restrict__ ldS, int* __restrict__ flag)
{
    __shared__ float Bs[DD][DD + 1];
    __shared__ float r[4][DD + 1];
    __shared__ float sinv[DD];
    __shared__ float part2[2];
    const int tid = threadIdx.x;
    const int s   = blockIdx.x >> 5;
    const int i0  = (blockIdx.x & 31) * 4;

    int gid = (blockIdx.x * 128 + tid) * 4;
    int f = 0;
    #pragma unroll
    for (int t = 0; t < 4; ++t) {
        int idx = gid + t;
        if (idx < n_words) {
            unsigned int v = mw[idx];
            if (v > 1u) f |= 1;
            if (v == 0x3F800000u) f |= 2;
        }
    }
    unsigned long long bA = __ballot(f & 1);
    unsigned long long bB = __ballot(f & 2);
    if ((tid & 63) == 0) {
        int fw = (bA ? 1 : 0) | (bB ? 2 : 0);
        if (fw) atomicOr(flag, fw);
    }

    for (int idx = tid; idx < DD * DD; idx += 128) {
        int row = idx >> 7, col = idx & 127;
        Bs[row][col] = (row == col ? 1.f : 0.f) - W[idx];
    }
    sinv[tid] = 1.f / fmaxf(expf(ls2[s * DD + tid]), EPSF);
    __syncthreads();
    for (int a = 0; a < 4; ++a)
        r[a][tid] = Bs[i0 + a][tid] * sinv[tid];
    __syncthreads();

    const int j = tid;
    float acc0 = 0.f, acc1 = 0.f, acc2 = 0.f, acc3 = 0.f;
    #pragma unroll 4
    for (int d = 0; d < DD; ++d) {
        float bj = Bs[j][d];
        acc0 += r[0][d] * bj;
        acc1 += r[1][d] * bj;
        acc2 += r[2][d] * bj;
        acc3 += r[3][d] * bj;
    }
    size_t base = ((size_t)s * DD + i0) * DD + j;
    Q[base         ] = acc0;
    Q[base +     DD] = acc1;
    Q[base + 2 * DD] = acc2;
    Q[base + 3 * DD] = acc3;

    if (i0 == 0) {
        float v = logf(fmaxf(expf(ls2[s * DD + tid]), EPSF));
        for (int o = 32; o; o >>= 1) v += __shfl_down(v, o, 64);
        if ((tid & 63) == 0) part2[tid >> 6] = v;
        __syncthreads();
        if (tid == 0) ldS[s] = part2[0] + part2[1];
    }
}

// ---------------------------------------------------------------------------
// K2 fast: ONE WAVE (64 thr) per workgroup, TWO independent samples per wave
// (interleaved register chains -> mutual latency hiding). Per sample:
// bordered Cholesky of Q_mm (+u border), register-resident elements,
// column-major-from-right enumeration (alive slots = prefix; (m,m) = lane0
// slot0), scaled-column update, double-buffered csc, one barrier per step.
// ---------------------------------------------------------------------------
__global__ __launch_bounds__(64) void k_fast(
    const float* __restrict__ data, const float* __restrict__ mu,
    const float* __restrict__ wgt, const int* __restrict__ src,
    const void* __restrict__ miss, const int* __restrict__ layoutFlag,
    const float* __restrict__ Q, const float* __restrict__ ldS,
    float* __restrict__ partial, int* __restrict__ ovf_count,
    int* __restrict__ ovf_list, int half)
{
    __shared__ __align__(16) float xshA[DD], xshB[DD];
    __shared__ float yshA[DD], yshB[DD];
    __shared__ int   midxA[64], midxB[64];
    __shared__ float cscA[2][64], cscB[2][64];

    const int lane = threadIdx.x;
    const int iA = blockIdx.x;
    const int iB = blockIdx.x + half;
    const int sA = src[iA], sB = src[iB];
    const float* QA = Q + (size_t)sA * DD * DD;
    const float* QB = Q + (size_t)sB * DD * DD;
    const size_t baseA = (size_t)iA * DD;
    const size_t baseB = (size_t)iB * DD;

    // ---- mask decode (uniform branch on detected layout) ----
    const int f = *layoutFlag;
    bool a0m, a1m, b0m, b1m;
    if (f & 2) {
        const float* M = (const float*)miss;
        a0m = M[baseA + lane] != 0.f;  a1m = M[baseA + lane + 64] != 0.f;
        b0m = M[baseB + lane] != 0.f;  b1m = M[baseB + lane + 64] != 0.f;
    } else if (f & 1) {
        const unsigned char* M = (const unsigned char*)miss;
        a0m = M[baseA + lane] != 0;    a1m = M[baseA + lane + 64] != 0;
        b0m = M[baseB + lane] != 0;    b1m = M[baseB + lane + 64] != 0;
    } else {
        const int* M = (const int*)miss;
        a0m = M[baseA + lane] != 0;    a1m = M[baseA + lane + 64] != 0;
        b0m = M[baseB + lane] != 0;    b1m = M[baseB + lane + 64] != 0;
    }

    unsigned long long bA0 = __ballot(a0m), bA1 = __ballot(a1m);
    unsigned long long bB0 = __ballot(b0m), bB1 = __ballot(b1m);
    int mA = __popcll(bA0) + __popcll(bA1);
    int mB = __popcll(bB0) + __popcll(bB1);
    const bool skipA = (mA > MFAST), skipB = (mB > MFAST);
    if (lane == 0) {
        if (skipA) { int pos = atomicAdd(ovf_count, 1); ovf_list[pos] = iA; }
        if (skipB) { int pos = atomicAdd(ovf_count, 1); ovf_list[pos] = iB; }
    }
    if (skipA) mA = 0;
    if (skipB) mB = 0;

    unsigned long long lt = (1ull << lane) - 1ull;
    if (!skipA) {
        if (a0m) midxA[__popcll(bA0 & lt)] = lane;
        if (a1m) midxA[__popcll(bA0) + __popcll(bA1 & lt)] = lane + 64;
    }
    if (!skipB) {
        if (b0m) midxB[__popcll(bB0 & lt)] = lane;
        if (b1m) midxB[__popcll(bB0) + __popcll(bB1 & lt)] = lane + 64;
    }

    float xA0 = a0m ? 0.f : (data[baseA + lane]      - mu[lane]);
    float xA1 = a1m ? 0.f : (data[baseA + lane + 64] - mu[lane + 64]);
    float xB0 = b0m ? 0.f : (data[baseB + lane]      - mu[lane]);
    float xB1 = b1m ? 0.f : (data[baseB + lane + 64] - mu[lane + 64]);
    xshA[lane] = xA0;  xshA[lane + 64] = xA1;
    xshB[lane] = xB0;  xshB[lane + 64] = xB1;
    __syncthreads();

    // ---- y = Q x for both samples (8 independent streams of ILP) ----
    const float4* qa0 = (const float4*)(QA + (size_t)lane * DD);
    const float4* qa1 = (const float4*)(QA + (size_t)(lane + 64) * DD);
    const float4* qb0 = (const float4*)(QB + (size_t)lane * DD);
    const float4* qb1 = (const float4*)(QB + (size_t)(lane + 64) * DD);
    const float4* xa4 = (const float4*)xshA;
    const float4* xb4 = (const float4*)xshB;
    float accA0 = 0.f, accA1 = 0.f, accB0 = 0.f, accB1 = 0.f;
    #pragma unroll 8
    for (int d = 0; d < DD / 4; ++d) {
        float4 xa = xa4[d], xb = xb4[d];
        float4 q0 = qa0[d], q1 = qa1[d], q2 = qb0[d], q3 = qb1[d];
        accA0 += q0.x * xa.x + q0.y * xa.y + q0.z * xa.z + q0.w * xa.w;
        accA1 += q1.x * xa.x + q1.y * xa.y + q1.z * xa.z + q1.w * xa.w;
        accB0 += q2.x * xb.x + q2.y * xb.y + q2.z * xb.z + q2.w * xb.w;
        accB1 += q3.x * xb.x + q3.y * xb.y + q3.z * xb.z + q3.w * xb.w;
    }
    yshA[lane] = accA0;  yshA[lane + 64] = accA1;
    yshB[lane] = accB0;  yshB[lane + 64] = accB1;
    float pA = xA0 * accA0 + xA1 * accA1;
    float pB = xB0 * accB0 + xB1 * accB1;
    for (int o = 32; o; o >>= 1) {
        pA += __shfl_down(pA, o, 64);
        pB += __shfl_down(pB, o, 64);
    }
    __syncthreads();   // ysh, midx ready

    const int kmax = max(mA, mB);

    // ---- decode + load slots for both samples ----
    const int cntA_T = ((mA + 1) * (mA + 2)) >> 1;
    const int cntB_T = ((mB + 1) * (mB + 2)) >> 1;
    unsigned keyA[EMAX], keyB[EMAX];
    float    valA[EMAX], valB[EMAX];
    #pragma unroll
    for (int t = 0; t < EMAX; ++t) {
        keyA[t] = 0u; valA[t] = 0.f;
        keyB[t] = 0u; valB[t] = 0.f;
        int e = lane + (t << 6);
        if (e < cntA_T) {
            int q  = tri_row_of(e);
            int jc = mA - q;
            int ir = jc + (e - ((q * (q + 1)) >> 1));
            float v;
            if (ir == mA) v = (jc == mA) ? 0.f : yshA[midxA[jc]];
            else          v = QA[(size_t)(midxA[ir] * DD + midxA[jc])];
            keyA[t] = ((unsigned)jc << 8) | (unsigned)ir;
            valA[t] = v;
            if (jc == 0) cscA[0][ir] = v;
        }
        if (e < cntB_T) {
            int q  = tri_row_of(e);
            int jc = mB - q;
            int ir = jc + (e - ((q * (q + 1)) >> 1));
            float v;
            if (ir == mB) v = (jc == mB) ? 0.f : yshB[midxB[jc]];
            else          v = QB[(size_t)(midxB[ir] * DD + midxB[jc])];
            keyB[t] = ((unsigned)jc << 8) | (unsigned)ir;
            valB[t] = v;
            if (jc == 0) cscB[0][ir] = v;
        }
    }
    __syncthreads();

    // ---- interleaved wave-synchronous factorizations ----
    float logA = 0.f, logB = 0.f;
    #pragma unroll 1
    for (int k = 0; k < kmax; ++k) {
        const int pb = k & 1;
        const bool actA = (k < mA), actB = (k < mB);
        float invA = 1.f, invB = 1.f;
        if (actA) {
            float dk = cscA[pb][k];
            invA = __builtin_amdgcn_rcpf(dk);
            logA += __log2f(dk);
        }
        if (actB) {
            float dk = cscB[pb][k];
            invB = __builtin_amdgcn_rcpf(dk);
            logB += __log2f(dk);
        }
        const unsigned boundA = (unsigned)(k + 1) << 8;
        const unsigned boundB = (unsigned)(k + 2) << 8;
        #pragma unroll
        for (int t = 0; t < EMAX; ++t) {
            bool alA = actA && (keyA[t] >= boundA);
            bool alB = actB && (keyB[t] >= boundA);
            if (!__any(alA || alB)) break;
            if (alA) {
                int ir = (int)(keyA[t] & 255u);
                int jc = (int)(keyA[t] >> 8);
                float ci = cscA[pb][ir];
                float cj = cscA[pb][jc];
                valA[t] -= ci * cj * invA;
                if (keyA[t] < boundB) cscA[pb ^ 1][ir] = valA[t];
            }
            if (alB) {
                int ir = (int)(keyB[t] & 255u);
                int jc = (int)(keyB[t] >> 8);
                float ci = cscB[pb][ir];
                float cj = cscB[pb][jc];
                valB[t] -= ci * cj * invB;
                if (keyB[t] < boundB) cscB[pb ^ 1][ir] = valB[t];
            }
        }
        __syncthreads();
    }

    if (lane == 0) {
        float contrib = 0.f;
        if (!skipA) {
            float llA = -0.5f * ((pA + valA[0]) + logA * LN2F + ldS[sA]
                                 + (float)(DD - mA) * LOG_2PI);
            contrib += llA * wgt[iA];
        }
        if (!skipB) {
            float llB = -0.5f * ((pB + valB[0]) + logB * LN2F + ldS[sB]
                                 + (float)(DD - mB) * LOG_2PI);
            contrib += llB * wgt[iB];
        }
        atomicAdd(&partial[blockIdx.x & 63], contrib);
    }
}

// ---------------------------------------------------------------------------
// K tail: single block. (a) drain overflow list (m > MFAST; ~always empty)
// with the verified LDS-triangle Cholesky, (b) reduce partial -> out.
// ---------------------------------------------------------------------------
__global__ __launch_bounds__(128) void k_tail(
    const float* __restrict__ data, const float* __restrict__ mu,
    const float* __restrict__ wgt, const int* __restrict__ src,
    const void* __restrict__ miss, const int* __restrict__ layoutFlag,
    const float* __restrict__ Q, const float* __restrict__ ldS,
    float* __restrict__ partial, const int* __restrict__ ovf_count,
    const int* __restrict__ ovf_list, float* __restrict__ out)
{
    __shared__ __align__(16) float xsh[DD];
    __shared__ float ysh[DD];
    __shared__ int   midx[DD];
    __shared__ float cscv[DD + 1];
    __shared__ float tri[(DD + 1) * (DD + 2) / 2];
    __shared__ float bc[2];
    __shared__ float red[2];
    __shared__ int   sh_m;

    const int tid = threadIdx.x;
    const int novf = *ovf_count;
    for (int j = 0; j < novf; ++j) {
        const int i = ovf_list[j];
        if (tid == 0) sh_m = 0;
        __syncthreads();

        const int s = src[i];
        const float* Qs = Q + (size_t)s * DD * DD;
        const int f = *layoutFlag;
        const size_t g = (size_t)i * DD + tid;
        bool mm;
        if (f & 2)      mm = ((const float*)miss)[g] != 0.f;
        else if (f & 1) mm = ((const unsigned char*)miss)[g] != 0;
        else            mm = ((const int*)miss)[g] != 0;

        float xv = mm ? 0.f : (data[g] - mu[tid]);
        xsh[tid] = xv;
        if (mm) { int pos = atomicAdd(&sh_m, 1); midx[pos] = tid; }
        __syncthreads();
        const int m = sh_m;

        const float4* qrow = (const float4*)(Qs + (size_t)tid * DD);
        const float4* x4   = (const float4*)xsh;
        float acc = 0.f;
        #pragma unroll 8
        for (int d = 0; d < DD / 4; ++d) {
            float4 q = qrow[d], xx = x4[d];
            acc += q.x * xx.x + q.y * xx.y + q.z * xx.z + q.w * xx.w;
        }
        ysh[tid] = acc;
        float pp = xv * acc;
        for (int o = 32; o; o >>= 1) pp += __shfl_down(pp, o, 64);
        if ((tid & 63) == 0) red[tid >> 6] = pp;
        __syncthreads();

        const int cntA = (m * (m + 1)) >> 1;
        for (int e = tid; e < cntA; e += 128) {
            int a = tri_row_of(e);
            int b = e - ((a * (a + 1)) >> 1);
            tri[e] = Qs[(size_t)midx[a] * DD + midx[b]];
        }
        for (int b = tid; b < m; b += 128) tri[cntA + b] = ysh[midx[b]];
        if (tid == 0) tri[cntA + m] = 0.f;
        __syncthreads();

        float logacc = 0.f;
        if (m > 0) {
            if (tid == 0) {
                float d0 = tri[0];
                bc[1] = d0;
                float sq = sqrtf(d0);
                bc[0] = 1.f / sq;
                tri[0] = sq;
            }
            __syncthreads();
            for (int k = 0; k < m; ++k) {
                float inv = bc[0];
                if (tid == 0) logacc += logf(bc[1]);
                for (int ii = k + 1 + tid; ii <= m; ii += 128) {
                    int off = (ii * (ii + 1)) >> 1;
                    float v = tri[off + k] * inv;
                    tri[off + k] = v;
                    cscv[ii] = v;
                }
                __syncthreads();
                int qn  = m - k;
                int cnt = (qn * (qn + 1)) >> 1;
                for (int e = tid; e < cnt; e += 128) {
                    int ri = tri_row_of(e);
                    int rj = e - ((ri * (ri + 1)) >> 1);
                    int ii = k + 1 + ri, jj = k + 1 + rj;
                    int off = (ii * (ii + 1)) >> 1;
                    float v = tri[off + jj] - cscv[ii] * cscv[jj];
                    if (ii == jj && jj == k + 1 && k + 1 < m) {
                        bc[1] = v;
                        float sq = sqrtf(v);
                        bc[0] = 1.f / sq;
                        tri[off + jj] = sq;
                    } else {
                        tri[off + jj] = v;
                    }
                }
                __syncthreads();
            }
        }

        if (tid == 0) {
            float quad2 = (m > 0) ? -tri[cntA + m] : 0.f;
            float quad1 = red[0] + red[1];
            float ll = -0.5f * ((quad1 - quad2) + logacc + ldS[s]
                                + (float)(DD - m) * LOG_2PI);
            atomicAdd(&partial[i & 63], ll * wgt[i]);
        }
        __syncthreads();
    }

    __syncthreads();
    if (tid < 64) {
        float v = partial[tid];
        for (int o = 32; o; o >>= 1) v += __shfl_down(v, o, 64);
        if (tid == 0) out[0] = v;
    }
}

// ---------------------------------------------------------------------------
extern "C" void kernel_launch(void* const* d_in, const int* in_sizes, int n_in,
                              void* d_out, int out_size, void* d_ws, size_t ws_size,
                              hipStream_t stream)
{
    const float* data = (const float*)d_in[0];
    const float* W    = (const float*)d_in[1];
    const float* ls2  = (const float*)d_in[2];
    const float* mu   = (const float*)d_in[3];
    const float* wgt  = (const float*)d_in[4];
    const int*   src  = (const int*)d_in[5];
    const void*  miss = (const void*)d_in[6];
    float* out = (float*)d_out;

    float* Q        = (float*)d_ws;                    // 512 KB
    float* ldS      = Q + (size_t)NSRC * DD * DD;      // 8 floats
    float* partial  = ldS + NSRC;                      // 64 floats
    int*   flag     = (int*)(partial + 64);            // 1 int
    int*   ovf_cnt  = flag + 1;                        // 1 int
    int*   ovf_list = flag + 2;                        // 4096 ints

    const int n       = in_sizes[0] / DD;              // 4096 samples
    const int n_words = (n * DD) / 4;                  // 131072
    const int half    = n / 2;

    hipMemsetAsync(partial, 0, 66 * sizeof(float), stream);
    hipLaunchKernelGGL(k_precompute, dim3(NSRC * 32), dim3(128), 0, stream,
                       W, ls2, (const unsigned int*)miss, n_words, Q, ldS, flag);
    hipLaunchKernelGGL(k_fast, dim3(half), dim3(64), 0, stream,
                       data, mu, wgt, src, miss, flag, Q, ldS,
                       partial, ovf_cnt, ovf_list, half);
    hipLaunchKernelGGL(k_tail, dim3(1), dim3(128), 0, stream,
                       data, mu, wgt, src, miss, flag, Q, ldS,
                       partial, ovf_cnt, ovf_list, out);
}

// Round 7
// 162.384 us; speedup vs baseline: 1.3271x; 1.3271x over previous
//
#include <hip/hip_runtime.h>
#include <math.h>

#define DD 128
#define NSRC 8
#define EMAX 32          // 32*64 = 2048 >= (m+1)(m+2)/2  ->  m <= 62 fast path
#define MFAST 62
#define LOG_2PI 1.83787706640934548356f
#define LN2F 0.69314718055994531f
#define EPSF 1e-6f

// e -> row index within a packed lower triangle (row r has r+1 elements).
__device__ inline int tri_row_of(int e) {
    float f = sqrtf(8.f * (float)e + 1.f);
    int r = (int)((f - 1.f) * 0.5f);
    if ((r + 1) * (r + 2) / 2 <= e) ++r;
    else if (r * (r + 1) / 2 > e) --r;
    return r;
}

// ---------------------------------------------------------------------------
// K1: fused  (a) miss_mask layout detect  (b) Q_s = (I-W) D^-1 (I-W)^T
//            (c) ldS[s] = logdet Sigma_s      (verified R2-R6)
// ---------------------------------------------------------------------------
__global__ __launch_bounds__(128) void k_precompute(
    const float* __restrict__ W, const float* __restrict__ ls2,
    const unsigned int* __restrict__ mw, int n_words,
    float* __restrict__ Q, float* __restrict__ ldS, int* __restrict__ flag)
{
    __shared__ float Bs[DD][DD + 1];
    __shared__ float r[4][DD + 1];
    __shared__ float sinv[DD];
    __shared__ float part2[2];
    const int tid = threadIdx.x;
    const int s   = blockIdx.x >> 5;
    const int i0  = (blockIdx.x & 31) * 4;

    int gid = (blockIdx.x * 128 + tid) * 4;
    int f = 0;
    #pragma unroll
    for (int t = 0; t < 4; ++t) {
        int idx = gid + t;
        if (idx < n_words) {
            unsigned int v = mw[idx];
            if (v > 1u) f |= 1;
            if (v == 0x3F800000u) f |= 2;
        }
    }
    unsigned long long bA = __ballot(f & 1);
    unsigned long long bB = __ballot(f & 2);
    if ((tid & 63) == 0) {
        int fw = (bA ? 1 : 0) | (bB ? 2 : 0);
        if (fw) atomicOr(flag, fw);
    }

    for (int idx = tid; idx < DD * DD; idx += 128) {
        int row = idx >> 7, col = idx & 127;
        Bs[row][col] = (row == col ? 1.f : 0.f) - W[idx];
    }
    sinv[tid] = 1.f / fmaxf(expf(ls2[s * DD + tid]), EPSF);
    __syncthreads();
    for (int a = 0; a < 4; ++a)
        r[a][tid] = Bs[i0 + a][tid] * sinv[tid];
    __syncthreads();

    const int j = tid;
    float acc0 = 0.f, acc1 = 0.f, acc2 = 0.f, acc3 = 0.f;
    #pragma unroll 4
    for (int d = 0; d < DD; ++d) {
        float bj = Bs[j][d];
        acc0 += r[0][d] * bj;
        acc1 += r[1][d] * bj;
        acc2 += r[2][d] * bj;
        acc3 += r[3][d] * bj;
    }
    size_t base = ((size_t)s * DD + i0) * DD + j;
    Q[base         ] = acc0;
    Q[base +     DD] = acc1;
    Q[base + 2 * DD] = acc2;
    Q[base + 3 * DD] = acc3;

    if (i0 == 0) {
        float v = logf(fmaxf(expf(ls2[s * DD + tid]), EPSF));
        for (int o = 32; o; o >>= 1) v += __shfl_down(v, o, 64);
        if ((tid & 63) == 0) part2[tid >> 6] = v;
        __syncthreads();
        if (tid == 0) ldS[s] = part2[0] + part2[1];
    }
}

// ---------------------------------------------------------------------------
// K2 fast: ONE WAVE per sample (R4 structure) with COALESCED global access:
//  - y = Qx by columns (Q symmetric): lane owns j=2*lane,2*lane+1; per k one
//    contiguous float2 row read; uniform skip of x_k==0 (missing) columns.
//  - Q_mm gathered row-wise (lanes scatter within one 512B row) into a packed
//    LDS triangle; register slots fill from LDS.
//  - Cholesky: register-resident slots, column-major-from-right, scaled-column
//    update, double-buffered csc, one barrier per step (verified R4).
// ---------------------------------------------------------------------------
__global__ __launch_bounds__(64) void k_fast(
    const float* __restrict__ data, const float* __restrict__ mu,
    const float* __restrict__ wgt, const int* __restrict__ src,
    const void* __restrict__ miss, const int* __restrict__ layoutFlag,
    const float* __restrict__ Q, const float* __restrict__ ldS,
    float* __restrict__ partial, int* __restrict__ ovf_count,
    int* __restrict__ ovf_list)
{
    __shared__ float xsh[DD];
    __shared__ float ysh[DD];
    __shared__ int   midx[64];
    __shared__ float csc[2][64];
    __shared__ float tri[(MFAST + 1) * (MFAST + 2) / 2];   // 2016 floats

    const int i = blockIdx.x, lane = threadIdx.x;
    const int s = src[i];
    const float* Qs = Q + (size_t)s * DD * DD;
    const size_t base = (size_t)i * DD;
    const int j0 = 2 * lane, j1 = 2 * lane + 1;

    // ---- mask decode (uniform branch on detected layout) ----
    const int f = *layoutFlag;
    bool mmE, mmO;
    if (f & 2) {
        const float* M = (const float*)miss;
        mmE = M[base + j0] != 0.f;  mmO = M[base + j1] != 0.f;
    } else if (f & 1) {
        const unsigned char* M = (const unsigned char*)miss;
        mmE = M[base + j0] != 0;    mmO = M[base + j1] != 0;
    } else {
        const int* M = (const int*)miss;
        mmE = M[base + j0] != 0;    mmO = M[base + j1] != 0;
    }

    unsigned long long bE = __ballot(mmE), bO = __ballot(mmO);
    const int m = __popcll(bE) + __popcll(bO);
    if (m > MFAST) {
        if (lane == 0) { int pos = atomicAdd(ovf_count, 1); ovf_list[pos] = i; }
        return;
    }
    unsigned long long lt = (1ull << lane) - 1ull;
    if (mmE) midx[__popcll(bE & lt)] = j0;
    if (mmO) midx[__popcll(bE) + __popcll(bO & lt)] = j1;

    float x0 = mmE ? 0.f : (data[base + j0] - mu[j0]);
    float x1 = mmO ? 0.f : (data[base + j1] - mu[j1]);
    xsh[j0] = x0;
    xsh[j1] = x1;
    __syncthreads();

    // ---- y = Qx by columns: coalesced float2 row reads ----
    float y0 = 0.f, y1 = 0.f;
    #pragma unroll 4
    for (int k = 0; k < DD; ++k) {
        float xk = xsh[k];                      // broadcast
        if (xk != 0.f) {                        // wave-uniform skip
            float2 q = *(const float2*)(Qs + (size_t)k * DD + j0);
            y0 += xk * q.x;
            y1 += xk * q.y;
        }
    }
    ysh[j0] = y0;
    ysh[j1] = y1;
    float p = x0 * y0 + x1 * y1;
    for (int o = 32; o; o >>= 1) p += __shfl_down(p, o, 64);   // lane0: x^T Q x
    __syncthreads();   // ysh ready

    // ---- stage bordered triangle into LDS (coalesced row-wise gather) ----
    const int mjc = midx[lane];                 // own column index (valid lane<m)
    for (int ir = 0; ir < m; ++ir) {
        int row = midx[ir];                     // broadcast
        if (lane <= ir)
            tri[((ir * (ir + 1)) >> 1) + lane] = Qs[(size_t)row * DD + mjc];
    }
    const int offm = (m * (m + 1)) >> 1;
    if (lane < m)   tri[offm + lane] = ysh[mjc];   // border row = u
    if (lane == 0)  tri[offm + m] = 0.f;
    __syncthreads();

    // ---- fill register slots (column-major from rightmost column) ----
    const int cntT = ((m + 1) * (m + 2)) >> 1;
    unsigned key[EMAX];
    float    val[EMAX];
    #pragma unroll
    for (int t = 0; t < EMAX; ++t) {
        key[t] = 0u; val[t] = 0.f;
        int e = lane + (t << 6);
        if (e < cntT) {
            int q  = tri_row_of(e);            // q = m - col
            int jc = m - q;                    // column
            int ir = jc + (e - ((q * (q + 1)) >> 1));   // row, jc..m
            float v = tri[((ir * (ir + 1)) >> 1) + jc];
            key[t] = ((unsigned)jc << 8) | (unsigned)ir;
            val[t] = v;
            if (jc == 0) csc[0][ir] = v;       // column 0 seeds buffer A
        }
    }
    __syncthreads();

    // ---- wave-synchronous factorization: one barrier per step ----
    float logacc = 0.f;
    #pragma unroll 1
    for (int k = 0; k < m; ++k) {
        const int pb = k & 1;
        float dk = csc[pb][k];
        float invd = __builtin_amdgcn_rcpf(dk);
        logacc += __log2f(dk);
        const unsigned boundA = (unsigned)(k + 1) << 8;   // alive: key >= boundA
        const unsigned boundB = (unsigned)(k + 2) << 8;   // write: key <  boundB
        #pragma unroll
        for (int t = 0; t < EMAX; ++t) {
            bool alive = (key[t] >= boundA);
            if (!__any(alive)) break;
            if (alive) {
                int ir = (int)(key[t] & 255u);
                int jc = (int)(key[t] >> 8);
                float ci = csc[pb][ir];
                float cj = csc[pb][jc];
                val[t] -= ci * cj * invd;
                if (key[t] < boundB) csc[pb ^ 1][ir] = val[t];
            }
        }
        __syncthreads();
    }

    if (lane == 0) {
        // val[0] = element (m,m) = -u^T Qmm^{-1} u ; quad = p + val[0]
        float ll = -0.5f * ((p + val[0]) + logacc * LN2F + ldS[s]
                            + (float)(DD - m) * LOG_2PI);
        atomicAdd(&partial[i & 63], ll * wgt[i]);
    }
}

// ---------------------------------------------------------------------------
// K tail: single block. (a) drain overflow list (m > MFAST; ~always empty)
// with the verified LDS-triangle Cholesky, (b) reduce partial -> out.
// ---------------------------------------------------------------------------
__global__ __launch_bounds__(128) void k_tail(
    const float* __restrict__ data, const float* __restrict__ mu,
    const float* __restrict__ wgt, const int* __restrict__ src,
    const void* __restrict__ miss, const int* __restrict__ layoutFlag,
    const float* __restrict__ Q, const float* __restrict__ ldS,
    float* __restrict__ partial, const int* __restrict__ ovf_count,
    const int* __restrict__ ovf_list, float* __restrict__ out)
{
    __shared__ __align__(16) float xsh[DD];
    __shared__ float ysh[DD];
    __shared__ int   midx[DD];
    __shared__ float cscv[DD + 1];
    __shared__ float tri[(DD + 1) * (DD + 2) / 2];
    __shared__ float bc[2];
    __shared__ float red[2];
    __shared__ int   sh_m;

    const int tid = threadIdx.x;
    const int novf = *ovf_count;
    for (int j = 0; j < novf; ++j) {
        const int i = ovf_list[j];
        if (tid == 0) sh_m = 0;
        __syncthreads();

        const int s = src[i];
        const float* Qs = Q + (size_t)s * DD * DD;
        const int f = *layoutFlag;
        const size_t g = (size_t)i * DD + tid;
        bool mm;
        if (f & 2)      mm = ((const float*)miss)[g] != 0.f;
        else if (f & 1) mm = ((const unsigned char*)miss)[g] != 0;
        else            mm = ((const int*)miss)[g] != 0;

        float xv = mm ? 0.f : (data[g] - mu[tid]);
        xsh[tid] = xv;
        if (mm) { int pos = atomicAdd(&sh_m, 1); midx[pos] = tid; }
        __syncthreads();
        const int m = sh_m;

        const float4* qrow = (const float4*)(Qs + (size_t)tid * DD);
        const float4* x4   = (const float4*)xsh;
        float acc = 0.f;
        #pragma unroll 8
        for (int d = 0; d < DD / 4; ++d) {
            float4 q = qrow[d], xx = x4[d];
            acc += q.x * xx.x + q.y * xx.y + q.z * xx.z + q.w * xx.w;
        }
        ysh[tid] = acc;
        float pp = xv * acc;
        for (int o = 32; o; o >>= 1) pp += __shfl_down(pp, o, 64);
        if ((tid & 63) == 0) red[tid >> 6] = pp;
        __syncthreads();

        const int cntA = (m * (m + 1)) >> 1;
        for (int e = tid; e < cntA; e += 128) {
            int a = tri_row_of(e);
            int b = e - ((a * (a + 1)) >> 1);
            tri[e] = Qs[(size_t)midx[a] * DD + midx[b]];
        }
        for (int b = tid; b < m; b += 128) tri[cntA + b] = ysh[midx[b]];
        if (tid == 0) tri[cntA + m] = 0.f;
        __syncthreads();

        float logacc = 0.f;
        if (m > 0) {
            if (tid == 0) {
                float d0 = tri[0];
                bc[1] = d0;
                float sq = sqrtf(d0);
                bc[0] = 1.f / sq;
                tri[0] = sq;
            }
            __syncthreads();
            for (int k = 0; k < m; ++k) {
                float inv = bc[0];
                if (tid == 0) logacc += logf(bc[1]);
                for (int ii = k + 1 + tid; ii <= m; ii += 128) {
                    int off = (ii * (ii + 1)) >> 1;
                    float v = tri[off + k] * inv;
                    tri[off + k] = v;
                    cscv[ii] = v;
                }
                __syncthreads();
                int qn  = m - k;
                int cnt = (qn * (qn + 1)) >> 1;
                for (int e = tid; e < cnt; e += 128) {
                    int ri = tri_row_of(e);
                    int rj = e - ((ri * (ri + 1)) >> 1);
                    int ii = k + 1 + ri, jj = k + 1 + rj;
                    int off = (ii * (ii + 1)) >> 1;
                    float v = tri[off + jj] - cscv[ii] * cscv[jj];
                    if (ii == jj && jj == k + 1 && k + 1 < m) {
                        bc[1] = v;
                        float sq = sqrtf(v);
                        bc[0] = 1.f / sq;
                        tri[off + jj] = sq;
                    } else {
                        tri[off + jj] = v;
                    }
                }
                __syncthreads();
            }
        }

        if (tid == 0) {
            float quad2 = (m > 0) ? -tri[cntA + m] : 0.f;
            float quad1 = red[0] + red[1];
            float ll = -0.5f * ((quad1 - quad2) + logacc + ldS[s]
                                + (float)(DD - m) * LOG_2PI);
            atomicAdd(&partial[i & 63], ll * wgt[i]);
        }
        __syncthreads();
    }

    __syncthreads();
    if (tid < 64) {
        float v = partial[tid];
        for (int o = 32; o; o >>= 1) v += __shfl_down(v, o, 64);
        if (tid == 0) out[0] = v;
    }
}

// ---------------------------------------------------------------------------
extern "C" void kernel_launch(void* const* d_in, const int* in_sizes, int n_in,
                              void* d_out, int out_size, void* d_ws, size_t ws_size,
                              hipStream_t stream)
{
    const float* data = (const float*)d_in[0];
    const float* W    = (const float*)d_in[1];
    const float* ls2  = (const float*)d_in[2];
    const float* mu   = (const float*)d_in[3];
    const float* wgt  = (const float*)d_in[4];
    const int*   src  = (const int*)d_in[5];
    const void*  miss = (const void*)d_in[6];
    float* out = (float*)d_out;

    float* Q        = (float*)d_ws;                    // 512 KB
    float* ldS      = Q + (size_t)NSRC * DD * DD;      // 8 floats
    float* partial  = ldS + NSRC;                      // 64 floats
    int*   flag     = (int*)(partial + 64);            // 1 int
    int*   ovf_cnt  = flag + 1;                        // 1 int
    int*   ovf_list = flag + 2;                        // 4096 ints

    const int n       = in_sizes[0] / DD;              // 4096 samples
    const int n_words = (n * DD) / 4;                  // 131072

    hipMemsetAsync(partial, 0, 66 * sizeof(float), stream);
    hipLaunchKernelGGL(k_precompute, dim3(NSRC * 32), dim3(128), 0, stream,
                       W, ls2, (const unsigned int*)miss, n_words, Q, ldS, flag);
    hipLaunchKernelGGL(k_fast, dim3(n), dim3(64), 0, stream,
                       data, mu, wgt, src, miss, flag, Q, ldS,
                       partial, ovf_cnt, ovf_list);
    hipLaunchKernelGGL(k_tail, dim3(1), dim3(128), 0, stream,
                       data, mu, wgt, src, miss, flag, Q, ldS,
                       partial, ovf_cnt, ovf_list, out);
}